// Round 17
// baseline (1123.138 us; speedup 1.0000x reference)
//
#include <hip/hip_runtime.h>
#include <math.h>

typedef long long ll;
typedef __attribute__((ext_vector_type(8))) short short8;
typedef __attribute__((ext_vector_type(4))) float f32x4;

#define NBATCH 4
#define TSEQ   4095
#define NTOK   4096
#define DMODEL 512
#define NHEAD  8
#define DHEAD  64
#define NLAND  256
#define INDIM  1024
#define KCONV  33
#define NBH    32
#define NSPLIT 8

// ---------------- helpers ----------------
__device__ __forceinline__ float bred(float* red, float v, int tid, int op){
  red[tid] = v; __syncthreads();
  for (int s = 128; s > 0; s >>= 1){
    if (tid < s) red[tid] = op ? fmaxf(red[tid], red[tid+s]) : (red[tid] + red[tid+s]);
    __syncthreads();
  }
  float r = red[0];
  __syncthreads();
  return r;
}

__device__ __forceinline__ short f2bf(float f){  // RNE f32->bf16
  unsigned u = __float_as_uint(f);
  u += 0x7fff + ((u>>16)&1);
  return (short)(u>>16);
}
__device__ __forceinline__ float bf2f(short s){
  return __uint_as_float(((unsigned)(unsigned short)s) << 16);
}

// async global -> LDS, 16B per lane; LDS dest must be wave-uniform
__device__ __forceinline__ void gload16(const void* g, void* l){
  __builtin_amdgcn_global_load_lds((const __attribute__((address_space(1))) void*)g,
                                   (__attribute__((address_space(3))) void*)l, 16, 0, 0);
}

// ---------------- PE table ----------------
__global__ __launch_bounds__(256) void pe_table_k(float* __restrict__ pe){
  int idx = blockIdx.x*256 + threadIdx.x;
  if (idx >= TSEQ*DMODEL) return;
  int c = idx & 511; int t = idx >> 9;
  const double NEG = -9.210340371976184 / 512.0;
  double div = exp((double)(c & ~1) * NEG);
  float ang = (float)((double)t * div);
  pe[idx] = (c & 1) ? cosf(ang) : sinf(ang);
}

// h[b,0,:] = cls
__global__ __launch_bounds__(256) void cls_k(float* __restrict__ h, const float* __restrict__ cls){
  int b = blockIdx.x; int tid = threadIdx.x;
  h[(ll)b*NTOK*DMODEL + tid]       = cls[tid];
  h[(ll)b*NTOK*DMODEL + 256 + tid] = cls[256 + tid];
}

// ---------------- tiled transpose f32 [K][N] -> bf16 [N][K] ----------------
__global__ __launch_bounds__(256) void transpose_bf16_k(const float* __restrict__ in, short* __restrict__ out,
                                                        int K, int N, ll sIn, ll sOut){
  __shared__ float t[64][65];
  int L = blockIdx.z;
  in  += (ll)L*sIn;
  out += (ll)L*sOut;
  int n0 = blockIdx.x*64, k0 = blockIdx.y*64;
  int tid = threadIdx.x;
  for (int e = tid; e < 4096; e += 256){
    int r = e >> 6, c = e & 63;
    t[r][c] = in[(ll)(k0 + r)*N + n0 + c];
  }
  __syncthreads();
  for (int e = tid; e < 4096; e += 256){
    int r = e >> 6, c = e & 63;
    out[(ll)(n0 + r)*K + k0 + c] = f2bf(t[c][r]);
  }
}

// ---------------- LayerNorm rows (D=512), fp32 in -> bf16 out ----------------
__global__ __launch_bounds__(256) void ln_rows_k(const float* __restrict__ in, short* __restrict__ out,
                                                 const float* __restrict__ sc, const float* __restrict__ bi){
  __shared__ float red[256];
  ll row = blockIdx.x;
  const float* xr = in + row*DMODEL;
  short* orow = out + row*DMODEL;
  int tid = threadIdx.x;
  float v0 = xr[tid], v1 = xr[tid+256];
  float mu = bred(red, v0+v1, tid, 0) * (1.f/512.f);
  float d0 = v0-mu, d1 = v1-mu;
  float var = bred(red, d0*d0 + d1*d1, tid, 0) * (1.f/512.f);
  float inv = 1.f / sqrtf(var + 1e-5f);
  orow[tid]     = f2bf(d0*inv*sc[tid]     + bi[tid]);
  orow[tid+256] = f2bf(d1*inv*sc[tid+256] + bi[tid+256]);
}

// ============ bf16 MFMA GEMM, templated operand dtypes + BK ============
// AB: 1 = A bf16 [M][K] (global_load_lds fast path when tile fully in-range), 0 = A fp32.
// BMODE: 0 = B fp32 [K][N], 1 = B bf16 [K][N], 2 = B bf16 [N][K] via global_load_lds.
// CB: C bf16/fp32.  SW: XCD chunk swizzle.
// flags: 1=+bias 2=relu 4=C=c0*E+c1*acc 8=+=C 16=fc1 row remap
//        32=also write C^T (ld 256) to Ctr via LDS bounce (BM=BN=64, CB=1 only)
//        64=+PE[t][col] (Ev = pe)  128=emit landmark means to qlg/klg (qkv GEMM)
template<int BM, int BN, int BK, int AB, int BMODE, int CB, int SW>
__global__ __launch_bounds__(256)
void mgemm(const void* __restrict__ Av, const void* __restrict__ Bv,
           void* __restrict__ Cv, const void* __restrict__ Ev,
           const float* __restrict__ bias,
           short* __restrict__ qlg, short* __restrict__ klg,
           short* __restrict__ Ctr,
           int Mr, int K, int lda, int ldb, int ldc,
           ll sA, ll sB, ll sC,
           float c0, float c1, int flags)
{
  constexpr int MI = BM/32, NJ = BN/32;
  constexpr int S8 = BK/8;                 // short8 per row
  constexpr int AIT = (BM*S8)/256;         // A staging iterations (256 thr)
  constexpr int BIT = (BN*S8)/256;         // B staging iterations
  constexpr int KC  = BK/32;               // mfma K chunks
  __shared__ __align__(16) short As[BM*BK];
  __shared__ __align__(16) short Bs[BN*BK];
  int z = blockIdx.z;
  int bx = blockIdx.x, by = blockIdx.y;
  if (SW){
    int nwg = gridDim.x*gridDim.y;
    int lin = by*gridDim.x + bx;
    int q = nwg >> 3, r = nwg & 7;
    int xcd = lin & 7, idx = lin >> 3;
    int wg = (xcd < r) ? (xcd*(q+1) + idx) : (r*(q+1) + (xcd - r)*q + idx);
    bx = wg % gridDim.x; by = wg / gridDim.x;
  }
  int n0 = bx*BN, m0 = by*BM;
  int tid = threadIdx.x;
  int lane = tid & 63, w = tid >> 6;
  int wr = w >> 1, wc = w & 1;
  int l15 = lane & 15, l4 = lane >> 4;
  bool fullM = (m0 + BM <= Mr);

  f32x4 acc[MI][NJ];
  #pragma unroll
  for (int i = 0; i < MI; i++)
    #pragma unroll
    for (int j = 0; j < NJ; j++) acc[i][j] = (f32x4){0.f,0.f,0.f,0.f};

  for (int k0 = 0; k0 < K; k0 += BK){
    // ---- stage A [BM][BK] ----
    if (AB && fullM){
      #pragma unroll
      for (int it = 0; it < AIT; ++it){
        int base8 = (w*AIT + it)*64;
        int ls = base8 + lane;
        int row = ls / S8, slot = ls % S8;
        const short* gp = (const short*)Av + (ll)z*sA + (ll)(m0 + row)*lda + k0 + ((slot ^ (row&7))<<3);
        gload16(gp, (char*)As + (ll)base8*16);
      }
    } else {
      #pragma unroll
      for (int it = 0; it < AIT; ++it){
        int tau = tid + 256*it;
        int row = tau / S8, slot = tau % S8;
        int grow = m0 + row;
        short8 v;
        if (AB){
          if (grow < Mr) v = *(const short8*)((const short*)Av + (ll)z*sA + (ll)grow*lda + k0 + slot*8);
          else v = (short8){0,0,0,0,0,0,0,0};
        } else {
          f32x4 p0 = {0.f,0.f,0.f,0.f}, p1 = {0.f,0.f,0.f,0.f};
          if (grow < Mr){
            const float* ap = (const float*)Av + (ll)z*sA + (ll)grow*lda + k0 + slot*8;
            p0 = *(const f32x4*)ap; p1 = *(const f32x4*)(ap+4);
          }
          v[0]=f2bf(p0[0]); v[1]=f2bf(p0[1]); v[2]=f2bf(p0[2]); v[3]=f2bf(p0[3]);
          v[4]=f2bf(p1[0]); v[5]=f2bf(p1[1]); v[6]=f2bf(p1[2]); v[7]=f2bf(p1[3]);
        }
        ((short8*)As)[row*S8 + (slot ^ (row&7))] = v;
      }
    }
    // ---- stage B -> Bs[n][k] ----
    if (BMODE == 2){
      #pragma unroll
      for (int it = 0; it < BIT; ++it){
        int base8 = (w*BIT + it)*64;
        int ls = base8 + lane;
        int n = ls / S8, slot = ls % S8;
        const short* gp = (const short*)Bv + (ll)z*sB + (ll)(n0 + n)*ldb + k0 + ((slot ^ (n&7))<<3);
        gload16(gp, (char*)Bs + (ll)base8*16);
      }
    } else {
      #pragma unroll
      for (int it = 0; it < BIT; ++it){
        int tau = tid + 256*it;
        int n = tau % BN, slot = tau / BN;
        short8 v;
        if (BMODE == 1){
          const short* bp = (const short*)Bv + (ll)z*sB + (ll)(k0 + slot*8)*ldb + n0 + n;
          #pragma unroll
          for (int i = 0; i < 8; i++) v[i] = bp[(ll)i*ldb];
        } else {
          const float* bp = (const float*)Bv + (ll)z*sB + (ll)(k0 + slot*8)*ldb + n0 + n;
          #pragma unroll
          for (int i = 0; i < 8; i++) v[i] = f2bf(bp[(ll)i*ldb]);
        }
        ((short8*)Bs)[n*S8 + (slot ^ (n&7))] = v;
      }
    }
    __syncthreads();   // drains vmcnt (global_load_lds) + lgkm
    #pragma unroll
    for (int kc = 0; kc < KC; kc++){
      short8 af[MI], bfr[NJ];
      #pragma unroll
      for (int i = 0; i < MI; i++){
        int row = wr*(BM/2) + i*16 + l15;
        int g = kc*4 + l4;
        af[i] = ((short8*)As)[row*S8 + (g ^ (row&7))];
      }
      #pragma unroll
      for (int j = 0; j < NJ; j++){
        int col = wc*(BN/2) + j*16 + l15;
        int g = kc*4 + l4;
        bfr[j] = ((short8*)Bs)[col*S8 + (g ^ (col&7))];
      }
      #pragma unroll
      for (int i = 0; i < MI; i++)
        #pragma unroll
        for (int j = 0; j < NJ; j++)
          acc[i][j] = __builtin_amdgcn_mfma_f32_16x16x32_bf16(af[i], bfr[j], acc[i][j], 0, 0, 0);
    }
    __syncthreads();
  }

  short* ct = (short*)As;   // staging LDS dead after K-loop; [64][65] bounce tile
  #pragma unroll
  for (int i = 0; i < MI; i++){
    int rbase = m0 + wr*(BM/2) + i*16 + l4*4;
    #pragma unroll
    for (int j = 0; j < NJ; j++){
      int col = n0 + wc*(BN/2) + j*16 + l15;
      #pragma unroll
      for (int r = 0; r < 4; r++){
        int m = rbase + r;
        if (m >= Mr) continue;
        float v = acc[i][j][r];
        if (flags & 4){
          float ev = CB ? bf2f(((const short*)Ev + (ll)z*sC)[(ll)m*ldc + col])
                        : ((const float*)Ev + (ll)z*sC)[(ll)m*ldc + col];
          v = c0 * ev + c1 * v;
        }
        if (flags & 1) v += bias[col];
        if (flags & 2) v = fmaxf(v, 0.f);
        int bq = m / TSEQ;
        int om = (flags & 16) ? (m + bq + 1) : m;
        if (flags & 64) v += ((const float*)Ev)[(ll)(m - bq*TSEQ)*DMODEL + col];
        ll ci = (ll)z*sC + (ll)om*ldc + col;
        if (CB){
          short* Cs = (short*)Cv;
          if (flags & 8) v += bf2f(Cs[ci]);
          short bv = f2bf(v);
          Cs[ci] = bv;
          if (flags & 32) ct[(m - m0)*65 + (col - n0)] = bv;
        } else {
          float* Cf = (float*)Cv;
          if (flags & 8) v += Cf[ci];
          Cf[ci] = v;
        }
      }
    }
  }

  // ---- C^T emission via LDS bounce (NS matrices: BM=BN=64, ldcT=256) ----
  if ((flags & 32) && CB){
    __syncthreads();
    int n  = tid >> 2;            // 0..63
    int mb = (tid & 3) << 4;      // 0,16,32,48
    short8 o0, o1;
    #pragma unroll
    for (int e = 0; e < 8; e++) o0[e] = ct[(mb + e)*65 + n];
    #pragma unroll
    for (int e = 0; e < 8; e++) o1[e] = ct[(mb + 8 + e)*65 + n];
    short* ctp = Ctr + (ll)z*sC + (ll)(n0 + n)*256 + m0 + mb;
    *(short8*)ctp = o0;
    *((short8*)ctp + 1) = o1;
  }

  // ---- fused landmark means (qkv GEMM only): 16-row groups, BM=64 -> 4 groups ----
  if (flags & 128){
    int b = m0 >> 12;
    int i0 = (m0 & 4095) >> 4;
    #pragma unroll
    for (int i = 0; i < MI; i++){
      int g = wr*2 + i;
      #pragma unroll
      for (int j = 0; j < NJ; j++){
        int col = n0 + wc*(BN/2) + j*16 + l15;
        float scol = acc[i][j][0] + acc[i][j][1] + acc[i][j][2] + acc[i][j][3];
        scol += __shfl_xor(scol, 16);
        scol += __shfl_xor(scol, 32);
        if (l4 == 0 && col < 1024){
          int hh = (col >> 6) & 7;
          int d  = col & 63;
          if (col < 512)
            qlg[(((ll)(b*8 + hh))*256 + i0 + g)*64 + d] = f2bf(scol * (0.125f/16.f));
          else
            klg[(((ll)(b*8 + hh))*256 + i0 + g)*64 + d] = f2bf(scol * (1.f/16.f));
        }
      }
    }
  }
}

// ====== fused attn2: scores (MFMA) + row softmax + bf16 out + colsum partials ======
__global__ __launch_bounds__(256)
void a2_fused_k(const short* __restrict__ ql, const short* __restrict__ kl,
                short* __restrict__ a2h, float* __restrict__ cspart)
{
  __shared__ __align__(16) short Qs[64*64];
  __shared__ __align__(16) short Ks[256*64];
  __shared__ float rmax[64][2];
  __shared__ float rsum[64][2];
  int bh = blockIdx.y, mb = blockIdx.x;
  int m0 = mb*64;
  const short* qlp = ql + (ll)bh*16384 + (ll)m0*64;
  const short* klp = kl + (ll)bh*16384;
  short* a2hp = a2h + (ll)bh*65536;
  int tid = threadIdx.x;
  int lane = tid & 63, w = tid >> 6;
  int wr = w >> 1, wc = w & 1;
  int l15 = lane & 15, l4 = lane >> 4;

  #pragma unroll
  for (int it = 0; it < 2; it++){
    int tau = tid + 256*it;
    int row = tau >> 3, slot = tau & 7;
    ((short8*)Qs)[row*8 + (slot ^ (row&7))] = *(const short8*)(qlp + (ll)row*64 + slot*8);
  }
  #pragma unroll
  for (int it = 0; it < 8; it++){
    int tau = tid + 256*it;
    int row = tau >> 3, slot = tau & 7;
    ((short8*)Ks)[row*8 + (slot ^ (row&7))] = *(const short8*)(klp + (ll)row*64 + slot*8);
  }
  __syncthreads();

  f32x4 s[4][2][2];
  #pragma unroll
  for (int c = 0; c < 4; c++)
    #pragma unroll
    for (int i = 0; i < 2; i++)
      #pragma unroll
      for (int j = 0; j < 2; j++) s[c][i][j] = (f32x4){0.f,0.f,0.f,0.f};

  __builtin_amdgcn_s_setprio(1);
  #pragma unroll
  for (int kc = 0; kc < 2; kc++){
    int g = kc*4 + l4;
    short8 aq[2];
    #pragma unroll
    for (int i = 0; i < 2; i++){
      int row = wr*32 + i*16 + l15;
      aq[i] = ((short8*)Qs)[row*8 + (g ^ (row&7))];
    }
    #pragma unroll
    for (int c = 0; c < 4; c++){
      short8 bk[2];
      #pragma unroll
      for (int j = 0; j < 2; j++){
        int key = c*64 + wc*32 + j*16 + l15;
        bk[j] = ((short8*)Ks)[key*8 + (g ^ (key&7))];
      }
      #pragma unroll
      for (int i = 0; i < 2; i++)
        #pragma unroll
        for (int j = 0; j < 2; j++)
          s[c][i][j] = __builtin_amdgcn_mfma_f32_16x16x32_bf16(aq[i], bk[j], s[c][i][j], 0, 0, 0);
    }
  }
  __builtin_amdgcn_s_setprio(0);

  float mrow[2][4];
  #pragma unroll
  for (int i = 0; i < 2; i++)
    #pragma unroll
    for (int r = 0; r < 4; r++){
      float m = -1e30f;
      #pragma unroll
      for (int c = 0; c < 4; c++)
        #pragma unroll
        for (int j = 0; j < 2; j++) m = fmaxf(m, s[c][i][j][r]);
      m = fmaxf(m, __shfl_xor(m, 1));
      m = fmaxf(m, __shfl_xor(m, 2));
      m = fmaxf(m, __shfl_xor(m, 4));
      m = fmaxf(m, __shfl_xor(m, 8));
      mrow[i][r] = m;
    }
  if (l15 == 0){
    #pragma unroll
    for (int i = 0; i < 2; i++)
      #pragma unroll
      for (int r = 0; r < 4; r++)
        rmax[wr*32 + i*16 + l4*4 + r][wc] = mrow[i][r];
  }
  __syncthreads();
  float lsum[2][4];
  #pragma unroll
  for (int i = 0; i < 2; i++)
    #pragma unroll
    for (int r = 0; r < 4; r++){
      int row = wr*32 + i*16 + l4*4 + r;
      float m = fmaxf(rmax[row][0], rmax[row][1]);
      float ls = 0.f;
      #pragma unroll
      for (int c = 0; c < 4; c++)
        #pragma unroll
        for (int j = 0; j < 2; j++){
          float e = expf(s[c][i][j][r] - m);
          s[c][i][j][r] = e;
          ls += e;
        }
      ls += __shfl_xor(ls, 1);
      ls += __shfl_xor(ls, 2);
      ls += __shfl_xor(ls, 4);
      ls += __shfl_xor(ls, 8);
      lsum[i][r] = ls;
    }
  if (l15 == 0){
    #pragma unroll
    for (int i = 0; i < 2; i++)
      #pragma unroll
      for (int r = 0; r < 4; r++)
        rsum[wr*32 + i*16 + l4*4 + r][wc] = lsum[i][r];
  }
  __syncthreads();
  float csum[4][2];
  #pragma unroll
  for (int c = 0; c < 4; c++)
    #pragma unroll
    for (int j = 0; j < 2; j++) csum[c][j] = 0.f;
  #pragma unroll
  for (int i = 0; i < 2; i++)
    #pragma unroll
    for (int r = 0; r < 4; r++){
      int row = wr*32 + i*16 + l4*4 + r;
      float inv = 1.f/(rsum[row][0] + rsum[row][1]);
      #pragma unroll
      for (int c = 0; c < 4; c++)
        #pragma unroll
        for (int j = 0; j < 2; j++){
          float p = s[c][i][j][r] * inv;
          int col = c*64 + wc*32 + j*16 + l15;
          a2hp[(ll)(m0 + row)*256 + col] = f2bf(p);
          csum[c][j] += p;
        }
    }
  #pragma unroll
  for (int c = 0; c < 4; c++)
    #pragma unroll
    for (int j = 0; j < 2; j++){
      float v = csum[c][j];
      v += __shfl_xor(v, 16);
      v += __shfl_xor(v, 32);
      csum[c][j] = v;
    }
  if (l4 == 0){
    float* cp = cspart + (ll)(((bh*4 + mb)*2) + wr)*256;
    #pragma unroll
    for (int c = 0; c < 4; c++)
      #pragma unroll
      for (int j = 0; j < 2; j++)
        cp[c*64 + wc*32 + j*16 + l15] = csum[c][j];
  }
}

// denom: global max of column sums (row-sum max == 1 for softmax rows)
__global__ __launch_bounds__(256) void denom_k(const float* __restrict__ cspart, unsigned* __restrict__ scal){
  __shared__ float red[256];
  int bh = blockIdx.x;
  int tid = threadIdx.x;
  float s = 0.f;
  #pragma unroll
  for (int p = 0; p < 8; p++) s += cspart[(ll)(bh*8 + p)*256 + tid];
  float mx = bred(red, s, tid, 1);
  if (tid == 0) atomicMax(scal, __float_as_uint(mx));
}

// z0 = attn2^T / denom (strided) AND z0^T = attn2 / denom (contiguous)
__global__ __launch_bounds__(256) void zinit_k(const short* __restrict__ a2, short* __restrict__ z,
                                               short* __restrict__ zT, const unsigned* __restrict__ gm){
  float inv = 1.f / __uint_as_float(gm[0]);
  int base = blockIdx.x*1024 + threadIdx.x;
  #pragma unroll
  for (int u = 0; u < 4; u++){
    int idx = base + u*256;
    int j = idx & 255, i = (idx >> 8) & 255, bh = idx >> 16;
    z [idx] = f2bf(bf2f(a2[(ll)bh*65536 + j*256 + i]) * inv);
    zT[idx] = f2bf(bf2f(a2[idx]) * inv);
  }
}

// ================= MFMA flash attention, bf16 in (attn1: O bf16 normalized) =================
__global__ __launch_bounds__(256)
void mflash_k(const short* __restrict__ Q, const short* __restrict__ K,
              const short* __restrict__ V, short* __restrict__ O,
              int ldq, int ldk, int ldv, int ldo, int nkeys, float alpha,
              ll sQb, ll sQh, ll sKb, ll sKh, ll sVb, ll sVh, ll sOb, ll sOh)
{
  __shared__ __align__(16) short Qs[64*64];
  __shared__ __align__(16) short Ks[64*64];
  __shared__ __align__(16) short Vs[64*64];
  __shared__ __align__(16) short Ps[64*64];
  __shared__ float Sl[64][68];
  __shared__ float m_l[64], s_l[64], scl[64];
  int z = blockIdx.z; int b = z >> 3; int h = z & 7;
  Q += (ll)b*sQb + (ll)h*sQh;
  K += (ll)b*sKb + (ll)h*sKh;
  V += (ll)b*sVb + (ll)h*sVh;
  O += (ll)b*sOb + (ll)h*sOh;
  int m0 = blockIdx.x*64;
  int tid = threadIdx.x;
  int lane = tid & 63, w = tid >> 6;
  int l15 = lane & 15, l4 = lane >> 4;
  int wr = w >> 1, wc = w & 1;

  #pragma unroll
  for (int it = 0; it < 2; it++){
    int tau = tid + 256*it;
    int row = tau >> 3, slot = tau & 7;
    short8 v = *(const short8*)(Q + (ll)(m0 + row)*ldq + slot*8);
    ((short8*)Qs)[row*8 + (slot ^ (row&7))] = v;
  }
  if (tid < 64){ m_l[tid] = -1e30f; s_l[tid] = 0.f; }
  f32x4 o[2][2];
  #pragma unroll
  for (int i = 0; i < 2; i++)
    #pragma unroll
    for (int j = 0; j < 2; j++) o[i][j] = (f32x4){0.f,0.f,0.f,0.f};

  for (int n0 = 0; n0 < nkeys; n0 += 64){
    __syncthreads();
    #pragma unroll
    for (int it = 0; it < 2; it++){
      int tau = tid + 256*it;
      int row = tau >> 3, slot = tau & 7;
      short8 v = *(const short8*)(K + (ll)(n0 + row)*ldk + slot*8);
      ((short8*)Ks)[row*8 + (slot ^ (row&7))] = v;
    }
    #pragma unroll
    for (int it = 0; it < 2; it++){
      int key = (tid >> 3) + 32*it;
      int d0 = (tid & 7)*8;
      short8 v = *(const short8*)(V + (ll)(n0 + key)*ldv + d0);
      #pragma unroll
      for (int j = 0; j < 8; j++){
        int d = d0 + j;
        Vs[d*64 + (((key>>3) ^ (d&7))<<3) + (key&7)] = v[j];
      }
    }
    __syncthreads();
    f32x4 s[2][2];
    #pragma unroll
    for (int i = 0; i < 2; i++)
      #pragma unroll
      for (int j = 0; j < 2; j++) s[i][j] = (f32x4){0.f,0.f,0.f,0.f};
    __builtin_amdgcn_s_setprio(1);
    #pragma unroll
    for (int kc = 0; kc < 2; kc++){
      short8 aq[2], bk[2];
      int g = kc*4 + l4;
      #pragma unroll
      for (int i = 0; i < 2; i++){
        int row = wr*32 + i*16 + l15;
        aq[i] = ((short8*)Qs)[row*8 + (g ^ (row&7))];
      }
      #pragma unroll
      for (int j = 0; j < 2; j++){
        int key = wc*32 + j*16 + l15;
        bk[j] = ((short8*)Ks)[key*8 + (g ^ (key&7))];
      }
      #pragma unroll
      for (int i = 0; i < 2; i++)
        #pragma unroll
        for (int j = 0; j < 2; j++)
          s[i][j] = __builtin_amdgcn_mfma_f32_16x16x32_bf16(aq[i], bk[j], s[i][j], 0, 0, 0);
    }
    __builtin_amdgcn_s_setprio(0);
    #pragma unroll
    for (int i = 0; i < 2; i++)
      #pragma unroll
      for (int j = 0; j < 2; j++)
        #pragma unroll
        for (int r = 0; r < 4; r++)
          Sl[wr*32 + i*16 + l4*4 + r][wc*32 + j*16 + l15] = s[i][j][r] * alpha;
    __syncthreads();
    {
      int row = tid >> 2, q = tid & 3, cb = q*16;
      float sv[16];
      float cmax = -1e30f;
      #pragma unroll
      for (int cc = 0; cc < 16; cc++){ sv[cc] = Sl[row][cb+cc]; cmax = fmaxf(cmax, sv[cc]); }
      cmax = fmaxf(cmax, __shfl_xor(cmax, 1));
      cmax = fmaxf(cmax, __shfl_xor(cmax, 2));
      float mprev = m_l[row];
      float newm = fmaxf(mprev, cmax);
      float lsum = 0.f;
      short8 pv0, pv1;
      #pragma unroll
      for (int cc = 0; cc < 8; cc++){ float e = expf(sv[cc]-newm); lsum += e; pv0[cc] = f2bf(e); }
      #pragma unroll
      for (int cc = 0; cc < 8; cc++){ float e = expf(sv[8+cc]-newm); lsum += e; pv1[cc] = f2bf(e); }
      lsum += __shfl_xor(lsum, 1);
      lsum += __shfl_xor(lsum, 2);
      ((short8*)Ps)[row*8 + ((2*q)   ^ (row&7))] = pv0;
      ((short8*)Ps)[row*8 + ((2*q+1) ^ (row&7))] = pv1;
      if (q == 0){
        float scale = expf(mprev - newm);
        m_l[row] = newm;
        s_l[row] = s_l[row]*scale + lsum;
        scl[row] = scale;
      }
    }
    __syncthreads();
    #pragma unroll
    for (int i = 0; i < 2; i++)
      #pragma unroll
      for (int r = 0; r < 4; r++){
        float sc = scl[wr*32 + i*16 + l4*4 + r];
        #pragma unroll
        for (int j = 0; j < 2; j++) o[i][j][r] *= sc;
      }
    __builtin_amdgcn_s_setprio(1);
    #pragma unroll
    for (int kc = 0; kc < 2; kc++){
      short8 ap[2], bv[2];
      int g = kc*4 + l4;
      #pragma unroll
      for (int i = 0; i < 2; i++){
        int row = wr*32 + i*16 + l15;
        ap[i] = ((short8*)Ps)[row*8 + (g ^ (row&7))];
      }
      #pragma unroll
      for (int j = 0; j < 2; j++){
        int d = wc*32 + j*16 + l15;
        bv[j] = ((short8*)Vs)[d*8 + (g ^ (d&7))];
      }
      #pragma unroll
      for (int i = 0; i < 2; i++)
        #pragma unroll
        for (int j = 0; j < 2; j++)
          o[i][j] = __builtin_amdgcn_mfma_f32_16x16x32_bf16(ap[i], bv[j], o[i][j], 0, 0, 0);
    }
    __builtin_amdgcn_s_setprio(0);
  }
  #pragma unroll
  for (int i = 0; i < 2; i++)
    #pragma unroll
    for (int j = 0; j < 2; j++)
      #pragma unroll
      for (int r = 0; r < 4; r++){
        int row = wr*32 + i*16 + l4*4 + r;
        int col = wc*32 + j*16 + l15;
        O[(ll)(m0 + row)*ldo + col] = f2bf(o[i][j][r] / s_l[row]);
      }
}

// ======= MFMA flash attn3 partial (bf16 in; fp32 unnormalized partials) =======
__global__ __launch_bounds__(256)
void mflash3_part_k(const short* __restrict__ Q, const short* __restrict__ K,
                    const short* __restrict__ V,
                    float* __restrict__ po, float* __restrict__ pm, float* __restrict__ pl,
                    int ldq, int ldk, int ldv,
                    ll sQb, ll sQh, ll sKb, ll sKh, ll sVb, ll sVh)
{
  __shared__ __align__(16) short Qs[64*64];
  __shared__ __align__(16) short Ks[64*64];
  __shared__ __align__(16) short Vs[64*64];
  __shared__ __align__(16) short Ps[64*64];
  __shared__ float Sl[64][68];
  __shared__ float m_l[64], s_l[64], scl[64];
  int z = blockIdx.z; int b = z >> 3; int h = z & 7;
  int split = blockIdx.y;
  Q += (ll)b*sQb + (ll)h*sQh;
  K += (ll)b*sKb + (ll)h*sKh;
  V += (ll)b*sVb + (ll)h*sVh;
  int m0 = blockIdx.x*64;
  int koff = split * (NTOK/NSPLIT);
  int tid = threadIdx.x;
  int lane = tid & 63, w = tid >> 6;
  int l15 = lane & 15, l4 = lane >> 4;
  int wr = w >> 1, wc = w & 1;

  #pragma unroll
  for (int it = 0; it < 2; it++){
    int tau = tid + 256*it;
    int row = tau >> 3, slot = tau & 7;
    short8 v = *(const short8*)(Q + (ll)(m0 + row)*ldq + slot*8);
    ((short8*)Qs)[row*8 + (slot ^ (row&7))] = v;
  }
  if (tid < 64){ m_l[tid] = -1e30f; s_l[tid] = 0.f; }
  f32x4 o[2][2];
  #pragma unroll
  for (int i = 0; i < 2; i++)
    #pragma unroll
    for (int j = 0; j < 2; j++) o[i][j] = (f32x4){0.f,0.f,0.f,0.f};

  for (int n0 = koff; n0 < koff + NTOK/NSPLIT; n0 += 64){
    __syncthreads();
    #pragma unroll
    for (int it = 0; it < 2; it++){
      int tau = tid + 256*it;
      int row = tau >> 3, slot = tau & 7;
      short8 v = *(const short8*)(K + (ll)(n0 + row)*ldk + slot*8);
      ((short8*)Ks)[row*8 + (slot ^ (row&7))] = v;
    }
    #pragma unroll
    for (int it = 0; it < 2; it++){
      int key = (tid >> 3) + 32*it;
      int d0 = (tid & 7)*8;
      short8 v = *(const short8*)(V + (ll)(n0 + key)*ldv + d0);
      #pragma unroll
      for (int j = 0; j < 8; j++){
        int d = d0 + j;
        Vs[d*64 + (((key>>3) ^ (d&7))<<3) + (key&7)] = v[j];
      }
    }
    __syncthreads();
    f32x4 s[2][2];
    #pragma unroll
    for (int i = 0; i < 2; i++)
      #pragma unroll
      for (int j = 0; j < 2; j++) s[i][j] = (f32x4){0.f,0.f,0.f,0.f};
    __builtin_amdgcn_s_setprio(1);
    #pragma unroll
    for (int kc = 0; kc < 2; kc++){
      short8 aq[2], bk[2];
      int g = kc*4 + l4;
      #pragma unroll
      for (int i = 0; i < 2; i++){
        int row = wr*32 + i*16 + l15;
        aq[i] = ((short8*)Qs)[row*8 + (g ^ (row&7))];
      }
      #pragma unroll
      for (int j = 0; j < 2; j++){
        int key = wc*32 + j*16 + l15;
        bk[j] = ((short8*)Ks)[key*8 + (g ^ (key&7))];
      }
      #pragma unroll
      for (int i = 0; i < 2; i++)
        #pragma unroll
        for (int j = 0; j < 2; j++)
          s[i][j] = __builtin_amdgcn_mfma_f32_16x16x32_bf16(aq[i], bk[j], s[i][j], 0, 0, 0);
    }
    __builtin_amdgcn_s_setprio(0);
    #pragma unroll
    for (int i = 0; i < 2; i++)
      #pragma unroll
      for (int j = 0; j < 2; j++)
        #pragma unroll
        for (int r = 0; r < 4; r++)
          Sl[wr*32 + i*16 + l4*4 + r][wc*32 + j*16 + l15] = s[i][j][r];
    __syncthreads();
    {
      int row = tid >> 2, q = tid & 3, cb = q*16;
      float sv[16];
      float cmax = -1e30f;
      #pragma unroll
      for (int cc = 0; cc < 16; cc++){ sv[cc] = Sl[row][cb+cc]; cmax = fmaxf(cmax, sv[cc]); }
      cmax = fmaxf(cmax, __shfl_xor(cmax, 1));
      cmax = fmaxf(cmax, __shfl_xor(cmax, 2));
      float mprev = m_l[row];
      float newm = fmaxf(mprev, cmax);
      float lsum = 0.f;
      short8 pv0, pv1;
      #pragma unroll
      for (int cc = 0; cc < 8; cc++){ float e = expf(sv[cc]-newm); lsum += e; pv0[cc] = f2bf(e); }
      #pragma unroll
      for (int cc = 0; cc < 8; cc++){ float e = expf(sv[8+cc]-newm); lsum += e; pv1[cc] = f2bf(e); }
      lsum += __shfl_xor(lsum, 1);
      lsum += __shfl_xor(lsum, 2);
      ((short8*)Ps)[row*8 + ((2*q)   ^ (row&7))] = pv0;
      ((short8*)Ps)[row*8 + ((2*q+1) ^ (row&7))] = pv1;
      if (q == 0){
        float scale = expf(mprev - newm);
        m_l[row] = newm;
        s_l[row] = s_l[row]*scale + lsum;
        scl[row] = scale;
      }
    }
    __syncthreads();
    #pragma unroll
    for (int i = 0; i < 2; i++)
      #pragma unroll
      for (int r = 0; r < 4; r++){
        float sc = scl[wr*32 + i*16 + l4*4 + r];
        #pragma unroll
        for (int j = 0; j < 2; j++) o[i][j][r] *= sc;
      }
    __builtin_amdgcn_s_setprio(1);
    #pragma unroll
    for (int kc = 0; kc < 2; kc++){
      short8 ap[2], bv[2];
      int g = kc*4 + l4;
      #pragma unroll
      for (int i = 0; i < 2; i++){
        int row = wr*32 + i*16 + l15;
        ap[i] = ((short8*)Ps)[row*8 + (g ^ (row&7))];
      }
      #pragma unroll
      for (int j = 0; j < 2; j++){
        int d = wc*32 + j*16 + l15;
        bv[j] = ((short8*)Vs)[d*8 + (g ^ (d&7))];
      }
      #pragma unroll
      for (int i = 0; i < 2; i++)
        #pragma unroll
        for (int j = 0; j < 2; j++)
          o[i][j] = __builtin_amdgcn_mfma_f32_16x16x32_bf16(ap[i], bv[j], o[i][j], 0, 0, 0);
    }
    __builtin_amdgcn_s_setprio(0);
  }
  int bs = z*NSPLIT + split;
  #pragma unroll
  for (int i = 0; i < 2; i++)
    #pragma unroll
    for (int j = 0; j < 2; j++)
      #pragma unroll
      for (int r = 0; r < 4; r++){
        int row = wr*32 + i*16 + l4*4 + r;
        int col = wc*32 + j*16 + l15;
        po[((ll)bs*NLAND + m0 + row)*64 + col] = o[i][j][r];
      }
  if (tid < 64){
    pm[(ll)bs*NLAND + m0 + tid] = m_l[tid];
    pl[(ll)bs*NLAND + m0 + tid] = s_l[tid];
  }
}

// combine splits -> av[bh][row][64] (bf16)
__global__ __launch_bounds__(256)
void flash3_comb_k(const float* __restrict__ po, const float* __restrict__ pm,
                   const float* __restrict__ pl, short* __restrict__ av){
  int bh = blockIdx.y;
  int row = blockIdx.x*4 + (threadIdx.x >> 6);
  int col = threadIdx.x & 63;
  float ms = -1e30f;
  float mv[NSPLIT];
  #pragma unroll
  for (int s = 0; s < NSPLIT; s++){
    mv[s] = pm[((ll)bh*NSPLIT + s)*NLAND + row];
    ms = fmaxf(ms, mv[s]);
  }
  float osum = 0.f, lsum = 0.f;
  #pragma unroll
  for (int s = 0; s < NSPLIT; s++){
    float wgt = expf(mv[s] - ms);
    osum += wgt * po[(((ll)bh*NSPLIT + s)*NLAND + row)*64 + col];
    lsum += wgt * pl[((ll)bh*NSPLIT + s)*NLAND + row];
  }
  av[((ll)bh*NLAND + row)*64 + col] = f2bf(osum / lsum);
}

// ---------------- depthwise conv: register-window, per-thread d column ----------------
__global__ __launch_bounds__(256) void dwconv_add_k(const short* __restrict__ qkv,
                                                    const float* __restrict__ cw, short* __restrict__ out){
  __shared__ float sv[160][64];
  int z = blockIdx.y; int b = z >> 3; int h = z & 7;
  int t0 = blockIdx.x * 128;
  int tid = threadIdx.x;
  const short* vbase = qkv + (ll)b*NTOK*1536 + 1024 + h*64;
  for (int e8 = tid; e8 < 1280; e8 += 256){
    int r = e8 >> 3, d8 = (e8 & 7)*8;
    int t = t0 - 16 + r;
    short8 v = (t >= 0 && t < NTOK) ? *(const short8*)(vbase + (ll)t*1536 + d8)
                                    : (short8){0,0,0,0,0,0,0,0};
    #pragma unroll
    for (int j = 0; j < 8; j++) sv[r][d8 + j] = bf2f(v[j]);
  }
  float wreg[KCONV];
  #pragma unroll
  for (int kk = 0; kk < KCONV; kk++) wreg[kk] = cw[h*KCONV + kk];
  __syncthreads();
  int d = tid & 63, g = tid >> 6;
  float vals[64];
  #pragma unroll
  for (int j = 0; j < 64; j++) vals[j] = sv[g*32 + j][d];
  short* obase = out + (ll)b*NTOK*512 + h*64 + d;
  #pragma unroll
  for (int t = 0; t < 32; t++){
    float s = 0.f;
    #pragma unroll
    for (int kk = 0; kk < KCONV; kk++) s += vals[t + kk]*wreg[kk];
    ll oi = (ll)(t0 + g*32 + t)*512;
    obase[oi] = f2bf(bf2f(obase[oi]) + s);
  }
}

// ---------------- final head ----------------
__global__ __launch_bounds__(256) void head_k(const float* __restrict__ hb, const float* __restrict__ fns,
      const float* __restrict__ fnb, const float* __restrict__ fw, const float* __restrict__ fb,
      float* __restrict__ out){
  __shared__ float red[256];
  int b = blockIdx.x;
  const float* xr = hb + (ll)b*NTOK*DMODEL;
  int tid = threadIdx.x;
  float v0 = xr[tid], v1 = xr[tid+256];
  float mu = bred(red, v0+v1, tid, 0) * (1.f/512.f);
  float d0 = v0-mu, d1 = v1-mu;
  float var = bred(red, d0*d0 + d1*d1, tid, 0) * (1.f/512.f);
  float inv = 1.f/sqrtf(var + 1e-5f);
  float y0 = d0*inv*fns[tid]     + fnb[tid];
  float y1 = d1*inv*fns[tid+256] + fnb[tid+256];
  float dot = bred(red, y0*fw[tid] + y1*fw[tid+256], tid, 0);
  if (tid == 0){
    float logit = dot + fb[0];
    float prob = 1.f/(1.f + expf(-logit));
    out[b] = logit; out[4+b] = prob; out[8+b] = (prob > 0.5f) ? 1.f : 0.f;
  }
}

// =============================================================================
extern "C" void kernel_launch(void* const* d_in, const int* in_sizes, int n_in,
                              void* d_out, int out_size, void* d_ws, size_t ws_size,
                              hipStream_t stream)
{
  (void)in_sizes; (void)n_in; (void)out_size;
  const float* data  = (const float*)d_in[0];
  const float* fc1_w = (const float*)d_in[1];
  const float* fc1_b = (const float*)d_in[2];
  const float* cls   = (const float*)d_in[3];
  const float* ln_s  = (const float*)d_in[4];
  const float* ln_b  = (const float*)d_in[5];
  const float* qkv_w = (const float*)d_in[6];
  const float* out_w = (const float*)d_in[7];
  const float* out_b = (const float*)d_in[8];
  const float* convw = (const float*)d_in[9];
  const float* fns   = (const float*)d_in[10];
  const float* fnb   = (const float*)d_in[11];
  const float* fcw   = (const float*)d_in[12];
  const float* fcb   = (const float*)d_in[13];
  float* out = (float*)d_out;
  float* ws  = (float*)d_ws;

  // ---- workspace layout ----
  float* h    = ws;                                   // 8,388,608 f
  short* xb   = (short*)(h + 8388608);                // 8,388,608 s
  short* qkvh = xb + 8388608;                         // 25,165,824 s
  short* ql   = qkvh + 25165824;                      //   524,288 s
  short* kl   = ql + 524288;                          //   524,288 s
  short* a2h  = kl + 524288;                          // 2,097,152 s
  short* zA   = a2h + 2097152;                        // 2,097,152 s
  short* zB   = zA + 2097152;                         // 2,097,152 s
  short* t1   = zB + 2097152;                         // 2,097,152 s
  short* t2   = t1 + 2097152;                         // 2,097,152 s
  short* t3   = t2 + 2097152;                         // 2,097,152 s
  short* av   = t3 + 2097152;                         //   524,288 s
  short* y2   = av + 524288;                          //   524,288 s
  float* po   = (float*)(y2 + 524288);                // 4,194,304 f
  float* pm   = po + 4194304;                         //    65,536 f
  float* pl   = pm + 65536;                           //    65,536 f
  float* pe   = pl + 65536;                           // 2,097,152 f
  short* fc1t  = (short*)(pe + 2097152);              //   524,288 s
  short* qkvt  = fc1t + 524288;                       // 1,572,864 s
  short* outt  = qkvt + 1572864;                      //   524,288 s
  short* zAT  = outt + 524288;                        // 2,097,152 s (transposed pinv)
  short* zBT  = zAT + 2097152;                        // 2,097,152 s
  short* t1T  = zBT + 2097152;                        // 2,097,152 s
  short* t2T  = t1T + 2097152;                        // 2,097,152 s
  short* t3T  = t2T + 2097152;                        // 2,097,152 s
  float* cspart = (float*)(t3T + 2097152);            //    65,536 f
  unsigned* scal = (unsigned*)(cspart + 65536);       // 2 slots (one per layer)

  const size_t NEED = (size_t)((char*)(scal + 2) - (char*)ws);
  if (ws_size < NEED) return;

  // ---- prep ----
  pe_table_k<<<(TSEQ*DMODEL + 255)/256, 256, 0, stream>>>(pe);
  transpose_bf16_k<<<dim3(8, 16, 1), 256, 0, stream>>>(fc1_w, fc1t, INDIM, DMODEL, 0, 0);
  transpose_bf16_k<<<dim3(24, 8, 2), 256, 0, stream>>>(qkv_w, qkvt, DMODEL, 1536,
                                                       (ll)DMODEL*1536, (ll)1536*DMODEL);
  transpose_bf16_k<<<dim3(8, 8, 2), 256, 0, stream>>>(out_w, outt, DMODEL, DMODEL,
                                                      (ll)DMODEL*DMODEL, (ll)DMODEL*DMODEL);
  hipMemsetAsync(scal, 0, 2*sizeof(unsigned), stream);

  // fc1: fp32 A direct (inline cvt), bf16 B^T, fused bias+relu+PE, row remap
  mgemm<64,128,64,0,2,0,1><<<dim3(4, 256, 1), 256, 0, stream>>>(
      data, fc1t, h, pe, fc1_b, nullptr, nullptr, nullptr,
      NBATCH*TSEQ, INDIM, INDIM, INDIM, DMODEL,
      0, 0, 0, 0.f, 0.f, 1|2|16|64);
  cls_k<<<4, 256, 0, stream>>>(h, cls);

  for (int L = 0; L < 2; L++){
    const float* ob = out_b + (ll)L*DMODEL;
    const float* cw = convw + (ll)L*NHEAD*KCONV;
    const short* qwt = qkvt + (ll)L*1536*DMODEL;
    const short* owt = outt + (ll)L*DMODEL*DMODEL;

    ln_rows_k<<<NBATCH*NTOK, 256, 0, stream>>>(h, xb, ln_s + L*DMODEL, ln_b + L*DMODEL);
    // qkv GEMM with fused landmark means (flag 128)
    mgemm<64,128,64,1,2,1,1><<<dim3(12, 256, 1), 256, 0, stream>>>(
        xb, qwt, qkvh, nullptr, nullptr, ql, kl, nullptr,
        NBATCH*NTOK, DMODEL, DMODEL, DMODEL, 1536,
        0, 0, 0, 0.f, 0.f, 128);

    // fused attn2 scores + softmax + bf16 + colsum partials, then denom + zinit
    a2_fused_k<<<dim3(4, 32), 256, 0, stream>>>(ql, kl, a2h, cspart);
    denom_k<<<32, 256, 0, stream>>>(cspart, scal + L);
    zinit_k<<<2048, 256, 0, stream>>>(a2h, zA, zAT, scal + L);

    // Newton-Schulz x6 (bf16 MFMA, BK=256, coalesced B via transposed copies)
    short *zc = zA, *zcT = zAT, *zn = zB, *znT = zBT;
    for (int it = 0; it < 6; it++){
      mgemm<64,64,256,1,2,1,0><<<dim3(4, 4, NBH), 256, 0, stream>>>(   // t1 = a2@z
          a2h, zcT, t1, nullptr, nullptr, nullptr, nullptr, t1T,
          256, 256, 256, 256, 256, 65536, 65536, 65536, 0.f, 0.f, 32);
      mgemm<64,64,256,1,2,1,0><<<dim3(4, 4, NBH), 256, 0, stream>>>(   // t2 = 7t1 - t1@t1
          t1, t1T, t2, t1, nullptr, nullptr, nullptr, t2T,
          256, 256, 256, 256, 256, 65536, 65536, 65536, 7.f, -1.f, 4|32);
      mgemm<64,64,256,1,2,1,0><<<dim3(4, 4, NBH), 256, 0, stream>>>(   // t3 = 15t1 - t1@t2
          t1, t2T, t3, t1, nullptr, nullptr, nullptr, t3T,
          256, 256, 256, 256, 256, 65536, 65536, 65536, 15.f, -1.f, 4|32);
      mgemm<64,64,256,1,2,1,0><<<dim3(4, 4, NBH), 256, 0, stream>>>(   // zn = 3.25z - 0.25 z@t3
          zc, t3T, zn, zc, nullptr, nullptr, nullptr, znT,
          256, 256, 256, 256, 256, 65536, 65536, 65536, 3.25f, -0.25f, 4|32);
      short* s;
      s = zc;  zc = zn;   zn = s;
      s = zcT; zcT = znT; znT = s;
    }

    // av = softmax(ql @ k^T) @ v  (key-split MFMA flash + combine)
    mflash3_part_k<<<dim3(4, NSPLIT, NBH), 256, 0, stream>>>(
        ql, qkvh + 512, qkvh + 1024, po, pm, pl,
        64, 1536, 1536,
        131072, 16384, (ll)NTOK*1536, 64, (ll)NTOK*1536, 64);
    flash3_comb_k<<<dim3(64, NBH), 256, 0, stream>>>(po, pm, pl, av);

    // y2 = pinv @ av  (single-shot BK=256, BMODE=1 unchanged)
    mgemm<64,64,256,1,1,1,0><<<dim3(1, 4, NBH), 256, 0, stream>>>(
        zc, av, y2, nullptr, nullptr, nullptr, nullptr, nullptr,
        256, 256, 256, 64, 64, 65536, 16384, 16384, 0.f, 0.f, 0);

    // xb = softmax(0.125 q @ kl^T) @ y2  (attn1)
    mflash_k<<<dim3(64, 1, NBH), 256, 0, stream>>>(
        qkvh, kl, y2, xb,
        1536, 64, 64, 512, NLAND, 0.125f,
        (ll)NTOK*1536, 64, 131072, 16384, 131072, 16384, (ll)NTOK*512, 64);

    // xb += depthwise_conv(v)
    dwconv_add_k<<<dim3(32, NBH), 256, 0, stream>>>(qkvh, cw, xb);

    // h = h + xb @ out_w + out_b
    mgemm<64,128,64,1,2,0,1><<<dim3(4, 256, 1), 256, 0, stream>>>(
        xb, owt, h, nullptr, ob, nullptr, nullptr, nullptr,
        NBATCH*NTOK, DMODEL, DMODEL, DMODEL, DMODEL,
        0, 0, 0, 0.f, 0.f, 1|8);
  }

  head_k<<<4, 256, 0, stream>>>(h, fns, fnb, fcw, fcb, out);
}

// Round 18
// 1061.400 us; speedup vs baseline: 1.0582x; 1.0582x over previous
//
#include <hip/hip_runtime.h>
#include <math.h>

typedef long long ll;
typedef __attribute__((ext_vector_type(8))) short short8;
typedef __attribute__((ext_vector_type(4))) float f32x4;

#define NBATCH 4
#define TSEQ   4095
#define NTOK   4096
#define DMODEL 512
#define NHEAD  8
#define DHEAD  64
#define NLAND  256
#define INDIM  1024
#define KCONV  33
#define NBH    32
#define NSPLIT 8

// ---------------- helpers ----------------
__device__ __forceinline__ float bred(float* red, float v, int tid, int op){
  red[tid] = v; __syncthreads();
  for (int s = 128; s > 0; s >>= 1){
    if (tid < s) red[tid] = op ? fmaxf(red[tid], red[tid+s]) : (red[tid] + red[tid+s]);
    __syncthreads();
  }
  float r = red[0];
  __syncthreads();
  return r;
}

__device__ __forceinline__ short f2bf(float f){  // RNE f32->bf16
  unsigned u = __float_as_uint(f);
  u += 0x7fff + ((u>>16)&1);
  return (short)(u>>16);
}
__device__ __forceinline__ float bf2f(short s){
  return __uint_as_float(((unsigned)(unsigned short)s) << 16);
}

// async global -> LDS, 16B per lane; LDS dest must be wave-uniform
__device__ __forceinline__ void gload16(const void* g, void* l){
  __builtin_amdgcn_global_load_lds((const __attribute__((address_space(1))) void*)g,
                                   (__attribute__((address_space(3))) void*)l, 16, 0, 0);
}

// ---------------- PE table ----------------
__global__ __launch_bounds__(256) void pe_table_k(float* __restrict__ pe){
  int idx = blockIdx.x*256 + threadIdx.x;
  if (idx >= TSEQ*DMODEL) return;
  int c = idx & 511; int t = idx >> 9;
  const double NEG = -9.210340371976184 / 512.0;
  double div = exp((double)(c & ~1) * NEG);
  float ang = (float)((double)t * div);
  pe[idx] = (c & 1) ? cosf(ang) : sinf(ang);
}

// h[b,0,:] = cls
__global__ __launch_bounds__(256) void cls_k(float* __restrict__ h, const float* __restrict__ cls){
  int b = blockIdx.x; int tid = threadIdx.x;
  h[(ll)b*NTOK*DMODEL + tid]       = cls[tid];
  h[(ll)b*NTOK*DMODEL + 256 + tid] = cls[256 + tid];
}

// ---------------- tiled transpose f32 [K][N] -> bf16 [N][K] ----------------
__global__ __launch_bounds__(256) void transpose_bf16_k(const float* __restrict__ in, short* __restrict__ out,
                                                        int K, int N, ll sIn, ll sOut){
  __shared__ float t[64][65];
  int L = blockIdx.z;
  in  += (ll)L*sIn;
  out += (ll)L*sOut;
  int n0 = blockIdx.x*64, k0 = blockIdx.y*64;
  int tid = threadIdx.x;
  for (int e = tid; e < 4096; e += 256){
    int r = e >> 6, c = e & 63;
    t[r][c] = in[(ll)(k0 + r)*N + n0 + c];
  }
  __syncthreads();
  for (int e = tid; e < 4096; e += 256){
    int r = e >> 6, c = e & 63;
    out[(ll)(n0 + r)*K + k0 + c] = f2bf(t[c][r]);
  }
}

// ---------------- LayerNorm rows (D=512), fp32 in -> bf16 out ----------------
__global__ __launch_bounds__(256) void ln_rows_k(const float* __restrict__ in, short* __restrict__ out,
                                                 const float* __restrict__ sc, const float* __restrict__ bi){
  __shared__ float red[256];
  ll row = blockIdx.x;
  const float* xr = in + row*DMODEL;
  short* orow = out + row*DMODEL;
  int tid = threadIdx.x;
  float v0 = xr[tid], v1 = xr[tid+256];
  float mu = bred(red, v0+v1, tid, 0) * (1.f/512.f);
  float d0 = v0-mu, d1 = v1-mu;
  float var = bred(red, d0*d0 + d1*d1, tid, 0) * (1.f/512.f);
  float inv = 1.f / sqrtf(var + 1e-5f);
  orow[tid]     = f2bf(d0*inv*sc[tid]     + bi[tid]);
  orow[tid+256] = f2bf(d1*inv*sc[tid+256] + bi[tid+256]);
}

// ============ bf16 MFMA GEMM, templated operand dtypes + BK ============
// AB: 1 = A bf16 [M][K] (global_load_lds fast path when tile fully in-range), 0 = A fp32.
// BMODE: 0 = B fp32 [K][N], 1 = B bf16 [K][N], 2 = B bf16 [N][K] via global_load_lds.
// CB: C bf16/fp32.  SW: XCD chunk swizzle.
// flags: 1=+bias 2=relu 4=C=c0*E+c1*acc 8=+=C 16=fc1 row remap 64=+PE[t][col] (Ev = pe)
//        128=emit landmark means to qlg/klg (qkv GEMM; requires BM=64, M batch-aligned)
template<int BM, int BN, int BK, int AB, int BMODE, int CB, int SW>
__global__ __launch_bounds__(256)
void mgemm(const void* __restrict__ Av, const void* __restrict__ Bv,
           void* __restrict__ Cv, const void* __restrict__ Ev,
           const float* __restrict__ bias,
           short* __restrict__ qlg, short* __restrict__ klg,
           int Mr, int K, int lda, int ldb, int ldc,
           ll sA, ll sB, ll sC,
           float c0, float c1, int flags)
{
  constexpr int MI = BM/32, NJ = BN/32;
  constexpr int S8 = BK/8;                 // short8 per row
  constexpr int AIT = (BM*S8)/256;         // A staging iterations (256 thr)
  constexpr int BIT = (BN*S8)/256;         // B staging iterations
  constexpr int KC  = BK/32;               // mfma K chunks
  __shared__ __align__(16) short As[BM*BK];
  __shared__ __align__(16) short Bs[BN*BK];
  int z = blockIdx.z;
  int bx = blockIdx.x, by = blockIdx.y;
  if (SW){
    int nwg = gridDim.x*gridDim.y;
    int lin = by*gridDim.x + bx;
    int q = nwg >> 3, r = nwg & 7;
    int xcd = lin & 7, idx = lin >> 3;
    int wg = (xcd < r) ? (xcd*(q+1) + idx) : (r*(q+1) + (xcd - r)*q + idx);
    bx = wg % gridDim.x; by = wg / gridDim.x;
  }
  int n0 = bx*BN, m0 = by*BM;
  int tid = threadIdx.x;
  int lane = tid & 63, w = tid >> 6;
  int wr = w >> 1, wc = w & 1;
  int l15 = lane & 15, l4 = lane >> 4;
  bool fullM = (m0 + BM <= Mr);

  f32x4 acc[MI][NJ];
  #pragma unroll
  for (int i = 0; i < MI; i++)
    #pragma unroll
    for (int j = 0; j < NJ; j++) acc[i][j] = (f32x4){0.f,0.f,0.f,0.f};

  for (int k0 = 0; k0 < K; k0 += BK){
    // ---- stage A [BM][BK] ----
    if (AB && fullM){
      #pragma unroll
      for (int it = 0; it < AIT; ++it){
        int base8 = (w*AIT + it)*64;
        int ls = base8 + lane;
        int row = ls / S8, slot = ls % S8;
        const short* gp = (const short*)Av + (ll)z*sA + (ll)(m0 + row)*lda + k0 + ((slot ^ (row&7))<<3);
        gload16(gp, (char*)As + (ll)base8*16);
      }
    } else {
      #pragma unroll
      for (int it = 0; it < AIT; ++it){
        int tau = tid + 256*it;
        int row = tau / S8, slot = tau % S8;
        int grow = m0 + row;
        short8 v;
        if (AB){
          if (grow < Mr) v = *(const short8*)((const short*)Av + (ll)z*sA + (ll)grow*lda + k0 + slot*8);
          else v = (short8){0,0,0,0,0,0,0,0};
        } else {
          f32x4 p0 = {0.f,0.f,0.f,0.f}, p1 = {0.f,0.f,0.f,0.f};
          if (grow < Mr){
            const float* ap = (const float*)Av + (ll)z*sA + (ll)grow*lda + k0 + slot*8;
            p0 = *(const f32x4*)ap; p1 = *(const f32x4*)(ap+4);
          }
          v[0]=f2bf(p0[0]); v[1]=f2bf(p0[1]); v[2]=f2bf(p0[2]); v[3]=f2bf(p0[3]);
          v[4]=f2bf(p1[0]); v[5]=f2bf(p1[1]); v[6]=f2bf(p1[2]); v[7]=f2bf(p1[3]);
        }
        ((short8*)As)[row*S8 + (slot ^ (row&7))] = v;
      }
    }
    // ---- stage B -> Bs[n][k] ----
    if (BMODE == 2){
      #pragma unroll
      for (int it = 0; it < BIT; ++it){
        int base8 = (w*BIT + it)*64;
        int ls = base8 + lane;
        int n = ls / S8, slot = ls % S8;
        const short* gp = (const short*)Bv + (ll)z*sB + (ll)(n0 + n)*ldb + k0 + ((slot ^ (n&7))<<3);
        gload16(gp, (char*)Bs + (ll)base8*16);
      }
    } else {
      #pragma unroll
      for (int it = 0; it < BIT; ++it){
        int tau = tid + 256*it;
        int n = tau % BN, slot = tau / BN;
        short8 v;
        if (BMODE == 1){
          const short* bp = (const short*)Bv + (ll)z*sB + (ll)(k0 + slot*8)*ldb + n0 + n;
          #pragma unroll
          for (int i = 0; i < 8; i++) v[i] = bp[(ll)i*ldb];
        } else {
          const float* bp = (const float*)Bv + (ll)z*sB + (ll)(k0 + slot*8)*ldb + n0 + n;
          #pragma unroll
          for (int i = 0; i < 8; i++) v[i] = f2bf(bp[(ll)i*ldb]);
        }
        ((short8*)Bs)[n*S8 + (slot ^ (n&7))] = v;
      }
    }
    __syncthreads();   // drains vmcnt (global_load_lds) + lgkm
    #pragma unroll
    for (int kc = 0; kc < KC; kc++){
      short8 af[MI], bfr[NJ];
      #pragma unroll
      for (int i = 0; i < MI; i++){
        int row = wr*(BM/2) + i*16 + l15;
        int g = kc*4 + l4;
        af[i] = ((short8*)As)[row*S8 + (g ^ (row&7))];
      }
      #pragma unroll
      for (int j = 0; j < NJ; j++){
        int col = wc*(BN/2) + j*16 + l15;
        int g = kc*4 + l4;
        bfr[j] = ((short8*)Bs)[col*S8 + (g ^ (col&7))];
      }
      #pragma unroll
      for (int i = 0; i < MI; i++)
        #pragma unroll
        for (int j = 0; j < NJ; j++)
          acc[i][j] = __builtin_amdgcn_mfma_f32_16x16x32_bf16(af[i], bfr[j], acc[i][j], 0, 0, 0);
    }
    __syncthreads();
  }

  #pragma unroll
  for (int i = 0; i < MI; i++){
    int rbase = m0 + wr*(BM/2) + i*16 + l4*4;
    #pragma unroll
    for (int j = 0; j < NJ; j++){
      int col = n0 + wc*(BN/2) + j*16 + l15;
      #pragma unroll
      for (int r = 0; r < 4; r++){
        int m = rbase + r;
        if (m >= Mr) continue;
        float v = acc[i][j][r];
        if (flags & 4){
          float ev = CB ? bf2f(((const short*)Ev + (ll)z*sC)[(ll)m*ldc + col])
                        : ((const float*)Ev + (ll)z*sC)[(ll)m*ldc + col];
          v = c0 * ev + c1 * v;
        }
        if (flags & 1) v += bias[col];
        if (flags & 2) v = fmaxf(v, 0.f);
        int bq = m / TSEQ;
        int om = (flags & 16) ? (m + bq + 1) : m;
        if (flags & 64) v += ((const float*)Ev)[(ll)(m - bq*TSEQ)*DMODEL + col];
        ll ci = (ll)z*sC + (ll)om*ldc + col;
        if (CB){
          short* Cs = (short*)Cv;
          if (flags & 8) v += bf2f(Cs[ci]);
          Cs[ci] = f2bf(v);
        } else {
          float* Cf = (float*)Cv;
          if (flags & 8) v += Cf[ci];
          Cf[ci] = v;
        }
      }
    }
  }

  // ---- fused landmark means (qkv GEMM only): 16-row groups, BM=64 -> 4 groups ----
  if (flags & 128){
    int b = m0 >> 12;
    int i0 = (m0 & 4095) >> 4;
    #pragma unroll
    for (int i = 0; i < MI; i++){
      int g = wr*2 + i;
      #pragma unroll
      for (int j = 0; j < NJ; j++){
        int col = n0 + wc*(BN/2) + j*16 + l15;
        float scol = acc[i][j][0] + acc[i][j][1] + acc[i][j][2] + acc[i][j][3];
        scol += __shfl_xor(scol, 16);
        scol += __shfl_xor(scol, 32);
        if (l4 == 0 && col < 1024){
          int hh = (col >> 6) & 7;
          int d  = col & 63;
          if (col < 512)
            qlg[(((ll)(b*8 + hh))*256 + i0 + g)*64 + d] = f2bf(scol * (0.125f/16.f));
          else
            klg[(((ll)(b*8 + hh))*256 + i0 + g)*64 + d] = f2bf(scol * (1.f/16.f));
        }
      }
    }
  }
}

// ====== fused attn2: scores (MFMA) + row softmax + bf16 out + colsum partials ======
__global__ __launch_bounds__(256)
void a2_fused_k(const short* __restrict__ ql, const short* __restrict__ kl,
                short* __restrict__ a2h, float* __restrict__ cspart)
{
  __shared__ __align__(16) short Qs[64*64];
  __shared__ __align__(16) short Ks[256*64];
  __shared__ float rmax[64][2];
  __shared__ float rsum[64][2];
  int bh = blockIdx.y, mb = blockIdx.x;
  int m0 = mb*64;
  const short* qlp = ql + (ll)bh*16384 + (ll)m0*64;
  const short* klp = kl + (ll)bh*16384;
  short* a2hp = a2h + (ll)bh*65536;
  int tid = threadIdx.x;
  int lane = tid & 63, w = tid >> 6;
  int wr = w >> 1, wc = w & 1;
  int l15 = lane & 15, l4 = lane >> 4;

  #pragma unroll
  for (int it = 0; it < 2; it++){
    int tau = tid + 256*it;
    int row = tau >> 3, slot = tau & 7;
    ((short8*)Qs)[row*8 + (slot ^ (row&7))] = *(const short8*)(qlp + (ll)row*64 + slot*8);
  }
  #pragma unroll
  for (int it = 0; it < 8; it++){
    int tau = tid + 256*it;
    int row = tau >> 3, slot = tau & 7;
    ((short8*)Ks)[row*8 + (slot ^ (row&7))] = *(const short8*)(klp + (ll)row*64 + slot*8);
  }
  __syncthreads();

  f32x4 s[4][2][2];
  #pragma unroll
  for (int c = 0; c < 4; c++)
    #pragma unroll
    for (int i = 0; i < 2; i++)
      #pragma unroll
      for (int j = 0; j < 2; j++) s[c][i][j] = (f32x4){0.f,0.f,0.f,0.f};

  __builtin_amdgcn_s_setprio(1);
  #pragma unroll
  for (int kc = 0; kc < 2; kc++){
    int g = kc*4 + l4;
    short8 aq[2];
    #pragma unroll
    for (int i = 0; i < 2; i++){
      int row = wr*32 + i*16 + l15;
      aq[i] = ((short8*)Qs)[row*8 + (g ^ (row&7))];
    }
    #pragma unroll
    for (int c = 0; c < 4; c++){
      short8 bk[2];
      #pragma unroll
      for (int j = 0; j < 2; j++){
        int key = c*64 + wc*32 + j*16 + l15;
        bk[j] = ((short8*)Ks)[key*8 + (g ^ (key&7))];
      }
      #pragma unroll
      for (int i = 0; i < 2; i++)
        #pragma unroll
        for (int j = 0; j < 2; j++)
          s[c][i][j] = __builtin_amdgcn_mfma_f32_16x16x32_bf16(aq[i], bk[j], s[c][i][j], 0, 0, 0);
    }
  }
  __builtin_amdgcn_s_setprio(0);

  float mrow[2][4];
  #pragma unroll
  for (int i = 0; i < 2; i++)
    #pragma unroll
    for (int r = 0; r < 4; r++){
      float m = -1e30f;
      #pragma unroll
      for (int c = 0; c < 4; c++)
        #pragma unroll
        for (int j = 0; j < 2; j++) m = fmaxf(m, s[c][i][j][r]);
      m = fmaxf(m, __shfl_xor(m, 1));
      m = fmaxf(m, __shfl_xor(m, 2));
      m = fmaxf(m, __shfl_xor(m, 4));
      m = fmaxf(m, __shfl_xor(m, 8));
      mrow[i][r] = m;
    }
  if (l15 == 0){
    #pragma unroll
    for (int i = 0; i < 2; i++)
      #pragma unroll
      for (int r = 0; r < 4; r++)
        rmax[wr*32 + i*16 + l4*4 + r][wc] = mrow[i][r];
  }
  __syncthreads();
  float lsum[2][4];
  #pragma unroll
  for (int i = 0; i < 2; i++)
    #pragma unroll
    for (int r = 0; r < 4; r++){
      int row = wr*32 + i*16 + l4*4 + r;
      float m = fmaxf(rmax[row][0], rmax[row][1]);
      float ls = 0.f;
      #pragma unroll
      for (int c = 0; c < 4; c++)
        #pragma unroll
        for (int j = 0; j < 2; j++){
          float e = expf(s[c][i][j][r] - m);
          s[c][i][j][r] = e;
          ls += e;
        }
      ls += __shfl_xor(ls, 1);
      ls += __shfl_xor(ls, 2);
      ls += __shfl_xor(ls, 4);
      ls += __shfl_xor(ls, 8);
      lsum[i][r] = ls;
    }
  if (l15 == 0){
    #pragma unroll
    for (int i = 0; i < 2; i++)
      #pragma unroll
      for (int r = 0; r < 4; r++)
        rsum[wr*32 + i*16 + l4*4 + r][wc] = lsum[i][r];
  }
  __syncthreads();
  float csum[4][2];
  #pragma unroll
  for (int c = 0; c < 4; c++)
    #pragma unroll
    for (int j = 0; j < 2; j++) csum[c][j] = 0.f;
  #pragma unroll
  for (int i = 0; i < 2; i++)
    #pragma unroll
    for (int r = 0; r < 4; r++){
      int row = wr*32 + i*16 + l4*4 + r;
      float inv = 1.f/(rsum[row][0] + rsum[row][1]);
      #pragma unroll
      for (int c = 0; c < 4; c++)
        #pragma unroll
        for (int j = 0; j < 2; j++){
          float p = s[c][i][j][r] * inv;
          int col = c*64 + wc*32 + j*16 + l15;
          a2hp[(ll)(m0 + row)*256 + col] = f2bf(p);
          csum[c][j] += p;
        }
    }
  #pragma unroll
  for (int c = 0; c < 4; c++)
    #pragma unroll
    for (int j = 0; j < 2; j++){
      float v = csum[c][j];
      v += __shfl_xor(v, 16);
      v += __shfl_xor(v, 32);
      csum[c][j] = v;
    }
  if (l4 == 0){
    float* cp = cspart + (ll)(((bh*4 + mb)*2) + wr)*256;
    #pragma unroll
    for (int c = 0; c < 4; c++)
      #pragma unroll
      for (int j = 0; j < 2; j++)
        cp[c*64 + wc*32 + j*16 + l15] = csum[c][j];
  }
}

// denom: global max of column sums (row-sum max == 1 for softmax rows)
__global__ __launch_bounds__(256) void denom_k(const float* __restrict__ cspart, unsigned* __restrict__ scal){
  __shared__ float red[256];
  int bh = blockIdx.x;
  int tid = threadIdx.x;
  float s = 0.f;
  #pragma unroll
  for (int p = 0; p < 8; p++) s += cspart[(ll)(bh*8 + p)*256 + tid];
  float mx = bred(red, s, tid, 1);
  if (tid == 0) atomicMax(scal, __float_as_uint(mx));
}

// z0 = attn2^T / denom (bf16 in/out)
__global__ __launch_bounds__(256) void zinit_k(const short* __restrict__ a2, short* __restrict__ z,
                                               const unsigned* __restrict__ gm){
  float inv = 1.f / __uint_as_float(gm[0]);
  int base = blockIdx.x*1024 + threadIdx.x;
  #pragma unroll
  for (int u = 0; u < 4; u++){
    int idx = base + u*256;
    int j = idx & 255, i = (idx >> 8) & 255, bh = idx >> 16;
    z[idx] = f2bf(bf2f(a2[(ll)bh*65536 + j*256 + i]) * inv);
  }
}

// ================= MFMA flash attention, bf16 in (attn1: O bf16 normalized) =================
__global__ __launch_bounds__(256)
void mflash_k(const short* __restrict__ Q, const short* __restrict__ K,
              const short* __restrict__ V, short* __restrict__ O,
              int ldq, int ldk, int ldv, int ldo, int nkeys, float alpha,
              ll sQb, ll sQh, ll sKb, ll sKh, ll sVb, ll sVh, ll sOb, ll sOh)
{
  __shared__ __align__(16) short Qs[64*64];
  __shared__ __align__(16) short Ks[64*64];
  __shared__ __align__(16) short Vs[64*64];
  __shared__ __align__(16) short Ps[64*64];
  __shared__ float Sl[64][68];
  __shared__ float m_l[64], s_l[64], scl[64];
  int z = blockIdx.z; int b = z >> 3; int h = z & 7;
  Q += (ll)b*sQb + (ll)h*sQh;
  K += (ll)b*sKb + (ll)h*sKh;
  V += (ll)b*sVb + (ll)h*sVh;
  O += (ll)b*sOb + (ll)h*sOh;
  int m0 = blockIdx.x*64;
  int tid = threadIdx.x;
  int lane = tid & 63, w = tid >> 6;
  int l15 = lane & 15, l4 = lane >> 4;
  int wr = w >> 1, wc = w & 1;

  #pragma unroll
  for (int it = 0; it < 2; it++){
    int tau = tid + 256*it;
    int row = tau >> 3, slot = tau & 7;
    short8 v = *(const short8*)(Q + (ll)(m0 + row)*ldq + slot*8);
    ((short8*)Qs)[row*8 + (slot ^ (row&7))] = v;
  }
  if (tid < 64){ m_l[tid] = -1e30f; s_l[tid] = 0.f; }
  f32x4 o[2][2];
  #pragma unroll
  for (int i = 0; i < 2; i++)
    #pragma unroll
    for (int j = 0; j < 2; j++) o[i][j] = (f32x4){0.f,0.f,0.f,0.f};

  for (int n0 = 0; n0 < nkeys; n0 += 64){
    __syncthreads();
    #pragma unroll
    for (int it = 0; it < 2; it++){
      int tau = tid + 256*it;
      int row = tau >> 3, slot = tau & 7;
      short8 v = *(const short8*)(K + (ll)(n0 + row)*ldk + slot*8);
      ((short8*)Ks)[row*8 + (slot ^ (row&7))] = v;
    }
    #pragma unroll
    for (int it = 0; it < 2; it++){
      int key = (tid >> 3) + 32*it;
      int d0 = (tid & 7)*8;
      short8 v = *(const short8*)(V + (ll)(n0 + key)*ldv + d0);
      #pragma unroll
      for (int j = 0; j < 8; j++){
        int d = d0 + j;
        Vs[d*64 + (((key>>3) ^ (d&7))<<3) + (key&7)] = v[j];
      }
    }
    __syncthreads();
    f32x4 s[2][2];
    #pragma unroll
    for (int i = 0; i < 2; i++)
      #pragma unroll
      for (int j = 0; j < 2; j++) s[i][j] = (f32x4){0.f,0.f,0.f,0.f};
    __builtin_amdgcn_s_setprio(1);
    #pragma unroll
    for (int kc = 0; kc < 2; kc++){
      short8 aq[2], bk[2];
      int g = kc*4 + l4;
      #pragma unroll
      for (int i = 0; i < 2; i++){
        int row = wr*32 + i*16 + l15;
        aq[i] = ((short8*)Qs)[row*8 + (g ^ (row&7))];
      }
      #pragma unroll
      for (int j = 0; j < 2; j++){
        int key = wc*32 + j*16 + l15;
        bk[j] = ((short8*)Ks)[key*8 + (g ^ (key&7))];
      }
      #pragma unroll
      for (int i = 0; i < 2; i++)
        #pragma unroll
        for (int j = 0; j < 2; j++)
          s[i][j] = __builtin_amdgcn_mfma_f32_16x16x32_bf16(aq[i], bk[j], s[i][j], 0, 0, 0);
    }
    __builtin_amdgcn_s_setprio(0);
    #pragma unroll
    for (int i = 0; i < 2; i++)
      #pragma unroll
      for (int j = 0; j < 2; j++)
        #pragma unroll
        for (int r = 0; r < 4; r++)
          Sl[wr*32 + i*16 + l4*4 + r][wc*32 + j*16 + l15] = s[i][j][r] * alpha;
    __syncthreads();
    {
      int row = tid >> 2, q = tid & 3, cb = q*16;
      float sv[16];
      float cmax = -1e30f;
      #pragma unroll
      for (int cc = 0; cc < 16; cc++){ sv[cc] = Sl[row][cb+cc]; cmax = fmaxf(cmax, sv[cc]); }
      cmax = fmaxf(cmax, __shfl_xor(cmax, 1));
      cmax = fmaxf(cmax, __shfl_xor(cmax, 2));
      float mprev = m_l[row];
      float newm = fmaxf(mprev, cmax);
      float lsum = 0.f;
      short8 pv0, pv1;
      #pragma unroll
      for (int cc = 0; cc < 8; cc++){ float e = expf(sv[cc]-newm); lsum += e; pv0[cc] = f2bf(e); }
      #pragma unroll
      for (int cc = 0; cc < 8; cc++){ float e = expf(sv[8+cc]-newm); lsum += e; pv1[cc] = f2bf(e); }
      lsum += __shfl_xor(lsum, 1);
      lsum += __shfl_xor(lsum, 2);
      ((short8*)Ps)[row*8 + ((2*q)   ^ (row&7))] = pv0;
      ((short8*)Ps)[row*8 + ((2*q+1) ^ (row&7))] = pv1;
      if (q == 0){
        float scale = expf(mprev - newm);
        m_l[row] = newm;
        s_l[row] = s_l[row]*scale + lsum;
        scl[row] = scale;
      }
    }
    __syncthreads();
    #pragma unroll
    for (int i = 0; i < 2; i++)
      #pragma unroll
      for (int r = 0; r < 4; r++){
        float sc = scl[wr*32 + i*16 + l4*4 + r];
        #pragma unroll
        for (int j = 0; j < 2; j++) o[i][j][r] *= sc;
      }
    __builtin_amdgcn_s_setprio(1);
    #pragma unroll
    for (int kc = 0; kc < 2; kc++){
      short8 ap[2], bv[2];
      int g = kc*4 + l4;
      #pragma unroll
      for (int i = 0; i < 2; i++){
        int row = wr*32 + i*16 + l15;
        ap[i] = ((short8*)Ps)[row*8 + (g ^ (row&7))];
      }
      #pragma unroll
      for (int j = 0; j < 2; j++){
        int d = wc*32 + j*16 + l15;
        bv[j] = ((short8*)Vs)[d*8 + (g ^ (d&7))];
      }
      #pragma unroll
      for (int i = 0; i < 2; i++)
        #pragma unroll
        for (int j = 0; j < 2; j++)
          o[i][j] = __builtin_amdgcn_mfma_f32_16x16x32_bf16(ap[i], bv[j], o[i][j], 0, 0, 0);
    }
    __builtin_amdgcn_s_setprio(0);
  }
  #pragma unroll
  for (int i = 0; i < 2; i++)
    #pragma unroll
    for (int j = 0; j < 2; j++)
      #pragma unroll
      for (int r = 0; r < 4; r++){
        int row = wr*32 + i*16 + l4*4 + r;
        int col = wc*32 + j*16 + l15;
        O[(ll)(m0 + row)*ldo + col] = f2bf(o[i][j][r] / s_l[row]);
      }
}

// ======= MFMA flash attn3 partial (bf16 in; fp32 unnormalized partials) =======
__global__ __launch_bounds__(256)
void mflash3_part_k(const short* __restrict__ Q, const short* __restrict__ K,
                    const short* __restrict__ V,
                    float* __restrict__ po, float* __restrict__ pm, float* __restrict__ pl,
                    int ldq, int ldk, int ldv,
                    ll sQb, ll sQh, ll sKb, ll sKh, ll sVb, ll sVh)
{
  __shared__ __align__(16) short Qs[64*64];
  __shared__ __align__(16) short Ks[64*64];
  __shared__ __align__(16) short Vs[64*64];
  __shared__ __align__(16) short Ps[64*64];
  __shared__ float Sl[64][68];
  __shared__ float m_l[64], s_l[64], scl[64];
  int z = blockIdx.z; int b = z >> 3; int h = z & 7;
  int split = blockIdx.y;
  Q += (ll)b*sQb + (ll)h*sQh;
  K += (ll)b*sKb + (ll)h*sKh;
  V += (ll)b*sVb + (ll)h*sVh;
  int m0 = blockIdx.x*64;
  int koff = split * (NTOK/NSPLIT);
  int tid = threadIdx.x;
  int lane = tid & 63, w = tid >> 6;
  int l15 = lane & 15, l4 = lane >> 4;
  int wr = w >> 1, wc = w & 1;

  #pragma unroll
  for (int it = 0; it < 2; it++){
    int tau = tid + 256*it;
    int row = tau >> 3, slot = tau & 7;
    short8 v = *(const short8*)(Q + (ll)(m0 + row)*ldq + slot*8);
    ((short8*)Qs)[row*8 + (slot ^ (row&7))] = v;
  }
  if (tid < 64){ m_l[tid] = -1e30f; s_l[tid] = 0.f; }
  f32x4 o[2][2];
  #pragma unroll
  for (int i = 0; i < 2; i++)
    #pragma unroll
    for (int j = 0; j < 2; j++) o[i][j] = (f32x4){0.f,0.f,0.f,0.f};

  for (int n0 = koff; n0 < koff + NTOK/NSPLIT; n0 += 64){
    __syncthreads();
    #pragma unroll
    for (int it = 0; it < 2; it++){
      int tau = tid + 256*it;
      int row = tau >> 3, slot = tau & 7;
      short8 v = *(const short8*)(K + (ll)(n0 + row)*ldk + slot*8);
      ((short8*)Ks)[row*8 + (slot ^ (row&7))] = v;
    }
    #pragma unroll
    for (int it = 0; it < 2; it++){
      int key = (tid >> 3) + 32*it;
      int d0 = (tid & 7)*8;
      short8 v = *(const short8*)(V + (ll)(n0 + key)*ldv + d0);
      #pragma unroll
      for (int j = 0; j < 8; j++){
        int d = d0 + j;
        Vs[d*64 + (((key>>3) ^ (d&7))<<3) + (key&7)] = v[j];
      }
    }
    __syncthreads();
    f32x4 s[2][2];
    #pragma unroll
    for (int i = 0; i < 2; i++)
      #pragma unroll
      for (int j = 0; j < 2; j++) s[i][j] = (f32x4){0.f,0.f,0.f,0.f};
    __builtin_amdgcn_s_setprio(1);
    #pragma unroll
    for (int kc = 0; kc < 2; kc++){
      short8 aq[2], bk[2];
      int g = kc*4 + l4;
      #pragma unroll
      for (int i = 0; i < 2; i++){
        int row = wr*32 + i*16 + l15;
        aq[i] = ((short8*)Qs)[row*8 + (g ^ (row&7))];
      }
      #pragma unroll
      for (int j = 0; j < 2; j++){
        int key = wc*32 + j*16 + l15;
        bk[j] = ((short8*)Ks)[key*8 + (g ^ (key&7))];
      }
      #pragma unroll
      for (int i = 0; i < 2; i++)
        #pragma unroll
        for (int j = 0; j < 2; j++)
          s[i][j] = __builtin_amdgcn_mfma_f32_16x16x32_bf16(aq[i], bk[j], s[i][j], 0, 0, 0);
    }
    __builtin_amdgcn_s_setprio(0);
    #pragma unroll
    for (int i = 0; i < 2; i++)
      #pragma unroll
      for (int j = 0; j < 2; j++)
        #pragma unroll
        for (int r = 0; r < 4; r++)
          Sl[wr*32 + i*16 + l4*4 + r][wc*32 + j*16 + l15] = s[i][j][r];
    __syncthreads();
    {
      int row = tid >> 2, q = tid & 3, cb = q*16;
      float sv[16];
      float cmax = -1e30f;
      #pragma unroll
      for (int cc = 0; cc < 16; cc++){ sv[cc] = Sl[row][cb+cc]; cmax = fmaxf(cmax, sv[cc]); }
      cmax = fmaxf(cmax, __shfl_xor(cmax, 1));
      cmax = fmaxf(cmax, __shfl_xor(cmax, 2));
      float mprev = m_l[row];
      float newm = fmaxf(mprev, cmax);
      float lsum = 0.f;
      short8 pv0, pv1;
      #pragma unroll
      for (int cc = 0; cc < 8; cc++){ float e = expf(sv[cc]-newm); lsum += e; pv0[cc] = f2bf(e); }
      #pragma unroll
      for (int cc = 0; cc < 8; cc++){ float e = expf(sv[8+cc]-newm); lsum += e; pv1[cc] = f2bf(e); }
      lsum += __shfl_xor(lsum, 1);
      lsum += __shfl_xor(lsum, 2);
      ((short8*)Ps)[row*8 + ((2*q)   ^ (row&7))] = pv0;
      ((short8*)Ps)[row*8 + ((2*q+1) ^ (row&7))] = pv1;
      if (q == 0){
        float scale = expf(mprev - newm);
        m_l[row] = newm;
        s_l[row] = s_l[row]*scale + lsum;
        scl[row] = scale;
      }
    }
    __syncthreads();
    #pragma unroll
    for (int i = 0; i < 2; i++)
      #pragma unroll
      for (int r = 0; r < 4; r++){
        float sc = scl[wr*32 + i*16 + l4*4 + r];
        #pragma unroll
        for (int j = 0; j < 2; j++) o[i][j][r] *= sc;
      }
    __builtin_amdgcn_s_setprio(1);
    #pragma unroll
    for (int kc = 0; kc < 2; kc++){
      short8 ap[2], bv[2];
      int g = kc*4 + l4;
      #pragma unroll
      for (int i = 0; i < 2; i++){
        int row = wr*32 + i*16 + l15;
        ap[i] = ((short8*)Ps)[row*8 + (g ^ (row&7))];
      }
      #pragma unroll
      for (int j = 0; j < 2; j++){
        int d = wc*32 + j*16 + l15;
        bv[j] = ((short8*)Vs)[d*8 + (g ^ (d&7))];
      }
      #pragma unroll
      for (int i = 0; i < 2; i++)
        #pragma unroll
        for (int j = 0; j < 2; j++)
          o[i][j] = __builtin_amdgcn_mfma_f32_16x16x32_bf16(ap[i], bv[j], o[i][j], 0, 0, 0);
    }
    __builtin_amdgcn_s_setprio(0);
  }
  int bs = z*NSPLIT + split;
  #pragma unroll
  for (int i = 0; i < 2; i++)
    #pragma unroll
    for (int j = 0; j < 2; j++)
      #pragma unroll
      for (int r = 0; r < 4; r++){
        int row = wr*32 + i*16 + l4*4 + r;
        int col = wc*32 + j*16 + l15;
        po[((ll)bs*NLAND + m0 + row)*64 + col] = o[i][j][r];
      }
  if (tid < 64){
    pm[(ll)bs*NLAND + m0 + tid] = m_l[tid];
    pl[(ll)bs*NLAND + m0 + tid] = s_l[tid];
  }
}

// combine splits -> av[bh][row][64] (bf16)
__global__ __launch_bounds__(256)
void flash3_comb_k(const float* __restrict__ po, const float* __restrict__ pm,
                   const float* __restrict__ pl, short* __restrict__ av){
  int bh = blockIdx.y;
  int row = blockIdx.x*4 + (threadIdx.x >> 6);
  int col = threadIdx.x & 63;
  float ms = -1e30f;
  float mv[NSPLIT];
  #pragma unroll
  for (int s = 0; s < NSPLIT; s++){
    mv[s] = pm[((ll)bh*NSPLIT + s)*NLAND + row];
    ms = fmaxf(ms, mv[s]);
  }
  float osum = 0.f, lsum = 0.f;
  #pragma unroll
  for (int s = 0; s < NSPLIT; s++){
    float wgt = expf(mv[s] - ms);
    osum += wgt * po[(((ll)bh*NSPLIT + s)*NLAND + row)*64 + col];
    lsum += wgt * pl[((ll)bh*NSPLIT + s)*NLAND + row];
  }
  av[((ll)bh*NLAND + row)*64 + col] = f2bf(osum / lsum);
}

// ---------------- depthwise conv: register-window, per-thread d column ----------------
__global__ __launch_bounds__(256) void dwconv_add_k(const short* __restrict__ qkv,
                                                    const float* __restrict__ cw, short* __restrict__ out){
  __shared__ float sv[160][64];
  int z = blockIdx.y; int b = z >> 3; int h = z & 7;
  int t0 = blockIdx.x * 128;
  int tid = threadIdx.x;
  const short* vbase = qkv + (ll)b*NTOK*1536 + 1024 + h*64;
  for (int e8 = tid; e8 < 1280; e8 += 256){
    int r = e8 >> 3, d8 = (e8 & 7)*8;
    int t = t0 - 16 + r;
    short8 v = (t >= 0 && t < NTOK) ? *(const short8*)(vbase + (ll)t*1536 + d8)
                                    : (short8){0,0,0,0,0,0,0,0};
    #pragma unroll
    for (int j = 0; j < 8; j++) sv[r][d8 + j] = bf2f(v[j]);
  }
  float wreg[KCONV];
  #pragma unroll
  for (int kk = 0; kk < KCONV; kk++) wreg[kk] = cw[h*KCONV + kk];
  __syncthreads();
  int d = tid & 63, g = tid >> 6;
  float vals[64];
  #pragma unroll
  for (int j = 0; j < 64; j++) vals[j] = sv[g*32 + j][d];
  short* obase = out + (ll)b*NTOK*512 + h*64 + d;
  #pragma unroll
  for (int t = 0; t < 32; t++){
    float s = 0.f;
    #pragma unroll
    for (int kk = 0; kk < KCONV; kk++) s += vals[t + kk]*wreg[kk];
    ll oi = (ll)(t0 + g*32 + t)*512;
    obase[oi] = f2bf(bf2f(obase[oi]) + s);
  }
}

// ---------------- final head ----------------
__global__ __launch_bounds__(256) void head_k(const float* __restrict__ hb, const float* __restrict__ fns,
      const float* __restrict__ fnb, const float* __restrict__ fw, const float* __restrict__ fb,
      float* __restrict__ out){
  __shared__ float red[256];
  int b = blockIdx.x;
  const float* xr = hb + (ll)b*NTOK*DMODEL;
  int tid = threadIdx.x;
  float v0 = xr[tid], v1 = xr[tid+256];
  float mu = bred(red, v0+v1, tid, 0) * (1.f/512.f);
  float d0 = v0-mu, d1 = v1-mu;
  float var = bred(red, d0*d0 + d1*d1, tid, 0) * (1.f/512.f);
  float inv = 1.f/sqrtf(var + 1e-5f);
  float y0 = d0*inv*fns[tid]     + fnb[tid];
  float y1 = d1*inv*fns[tid+256] + fnb[tid+256];
  float dot = bred(red, y0*fw[tid] + y1*fw[tid+256], tid, 0);
  if (tid == 0){
    float logit = dot + fb[0];
    float prob = 1.f/(1.f + expf(-logit));
    out[b] = logit; out[4+b] = prob; out[8+b] = (prob > 0.5f) ? 1.f : 0.f;
  }
}

// =============================================================================
extern "C" void kernel_launch(void* const* d_in, const int* in_sizes, int n_in,
                              void* d_out, int out_size, void* d_ws, size_t ws_size,
                              hipStream_t stream)
{
  (void)in_sizes; (void)n_in; (void)out_size;
  const float* data  = (const float*)d_in[0];
  const float* fc1_w = (const float*)d_in[1];
  const float* fc1_b = (const float*)d_in[2];
  const float* cls   = (const float*)d_in[3];
  const float* ln_s  = (const float*)d_in[4];
  const float* ln_b  = (const float*)d_in[5];
  const float* qkv_w = (const float*)d_in[6];
  const float* out_w = (const float*)d_in[7];
  const float* out_b = (const float*)d_in[8];
  const float* convw = (const float*)d_in[9];
  const float* fns   = (const float*)d_in[10];
  const float* fnb   = (const float*)d_in[11];
  const float* fcw   = (const float*)d_in[12];
  const float* fcb   = (const float*)d_in[13];
  float* out = (float*)d_out;
  float* ws  = (float*)d_ws;

  // ---- workspace layout ----
  float* h    = ws;                                   // 8,388,608 f
  short* xb   = (short*)(h + 8388608);                // 8,388,608 s
  short* qkvh = xb + 8388608;                         // 25,165,824 s
  short* ql   = qkvh + 25165824;                      //   524,288 s
  short* kl   = ql + 524288;                          //   524,288 s
  short* a2h  = kl + 524288;                          // 2,097,152 s
  short* zA   = a2h + 2097152;                        // 2,097,152 s
  short* zB   = zA + 2097152;                         // 2,097,152 s
  short* t1   = zB + 2097152;                         // 2,097,152 s
  short* t2   = t1 + 2097152;                         // 2,097,152 s
  short* t3   = t2 + 2097152;                         // 2,097,152 s
  short* av   = t3 + 2097152;                         //   524,288 s
  short* y2   = av + 524288;                          //   524,288 s
  float* po   = (float*)(y2 + 524288);                // 4,194,304 f
  float* pm   = po + 4194304;                         //    65,536 f
  float* pl   = pm + 65536;                           //    65,536 f
  float* pe   = pl + 65536;                           // 2,097,152 f
  short* fc1t  = (short*)(pe + 2097152);              //   524,288 s
  short* qkvt  = fc1t + 524288;                       // 1,572,864 s
  short* outt  = qkvt + 1572864;                      //   524,288 s
  float* cspart = (float*)(outt + 524288);            //    65,536 f
  unsigned* scal = (unsigned*)(cspart + 65536);       // 2 slots (one per layer)

  const size_t NEED = (size_t)((char*)(scal + 2) - (char*)ws);
  if (ws_size < NEED) return;

  // ---- prep ----
  pe_table_k<<<(TSEQ*DMODEL + 255)/256, 256, 0, stream>>>(pe);
  transpose_bf16_k<<<dim3(8, 16, 1), 256, 0, stream>>>(fc1_w, fc1t, INDIM, DMODEL, 0, 0);
  transpose_bf16_k<<<dim3(24, 8, 2), 256, 0, stream>>>(qkv_w, qkvt, DMODEL, 1536,
                                                       (ll)DMODEL*1536, (ll)1536*DMODEL);
  transpose_bf16_k<<<dim3(8, 8, 2), 256, 0, stream>>>(out_w, outt, DMODEL, DMODEL,
                                                      (ll)DMODEL*DMODEL, (ll)DMODEL*DMODEL);
  hipMemsetAsync(scal, 0, 2*sizeof(unsigned), stream);

  // fc1: fp32 A direct (inline cvt), bf16 B^T, fused bias+relu+PE, row remap
  mgemm<64,128,64,0,2,0,1><<<dim3(4, 256, 1), 256, 0, stream>>>(
      data, fc1t, h, pe, fc1_b, nullptr, nullptr,
      NBATCH*TSEQ, INDIM, INDIM, INDIM, DMODEL,
      0, 0, 0, 0.f, 0.f, 1|2|16|64);
  cls_k<<<4, 256, 0, stream>>>(h, cls);

  for (int L = 0; L < 2; L++){
    const float* ob = out_b + (ll)L*DMODEL;
    const float* cw = convw + (ll)L*NHEAD*KCONV;
    const short* qwt = qkvt + (ll)L*1536*DMODEL;
    const short* owt = outt + (ll)L*DMODEL*DMODEL;

    ln_rows_k<<<NBATCH*NTOK, 256, 0, stream>>>(h, xb, ln_s + L*DMODEL, ln_b + L*DMODEL);
    // qkv GEMM with fused landmark means (flag 128)
    mgemm<64,128,64,1,2,1,1><<<dim3(12, 256, 1), 256, 0, stream>>>(
        xb, qwt, qkvh, nullptr, nullptr, ql, kl,
        NBATCH*NTOK, DMODEL, DMODEL, DMODEL, 1536,
        0, 0, 0, 0.f, 0.f, 128);

    // fused attn2 scores + softmax + bf16 + colsum partials, then denom + zinit
    a2_fused_k<<<dim3(4, 32), 256, 0, stream>>>(ql, kl, a2h, cspart);
    denom_k<<<32, 256, 0, stream>>>(cspart, scal + L);
    zinit_k<<<2048, 256, 0, stream>>>(a2h, zA, scal + L);

    // Newton-Schulz x6 (bf16 MFMA, single-shot BK=256)
    short* zc = zA; short* zn = zB;
    for (int it = 0; it < 6; it++){
      mgemm<64,64,256,1,1,1,0><<<dim3(4, 4, NBH), 256, 0, stream>>>(   // t1 = a2@z
          a2h, zc, t1, nullptr, nullptr, nullptr, nullptr, 256, 256, 256, 256, 256,
          65536, 65536, 65536, 0.f, 0.f, 0);
      mgemm<64,64,256,1,1,1,0><<<dim3(4, 4, NBH), 256, 0, stream>>>(   // t2 = 7t1 - t1@t1
          t1, t1, t2, t1, nullptr, nullptr, nullptr, 256, 256, 256, 256, 256,
          65536, 65536, 65536, 7.f, -1.f, 4);
      mgemm<64,64,256,1,1,1,0><<<dim3(4, 4, NBH), 256, 0, stream>>>(   // t3 = 15t1 - t1@t2
          t1, t2, t3, t1, nullptr, nullptr, nullptr, 256, 256, 256, 256, 256,
          65536, 65536, 65536, 15.f, -1.f, 4);
      mgemm<64,64,256,1,1,1,0><<<dim3(4, 4, NBH), 256, 0, stream>>>(   // zn = 3.25z - 0.25 z@t3
          zc, t3, zn, zc, nullptr, nullptr, nullptr, 256, 256, 256, 256, 256,
          65536, 65536, 65536, 3.25f, -0.25f, 4);
      short* tmp = zc; zc = zn; zn = tmp;
    }

    // av = softmax(ql @ k^T) @ v  (key-split MFMA flash + combine)
    mflash3_part_k<<<dim3(4, NSPLIT, NBH), 256, 0, stream>>>(
        ql, qkvh + 512, qkvh + 1024, po, pm, pl,
        64, 1536, 1536,
        131072, 16384, (ll)NTOK*1536, 64, (ll)NTOK*1536, 64);
    flash3_comb_k<<<dim3(64, NBH), 256, 0, stream>>>(po, pm, pl, av);

    // y2 = pinv @ av  (single-shot BK=256)
    mgemm<64,64,256,1,1,1,0><<<dim3(1, 4, NBH), 256, 0, stream>>>(
        zc, av, y2, nullptr, nullptr, nullptr, nullptr, 256, 256, 256, 64, 64,
        65536, 16384, 16384, 0.f, 0.f, 0);

    // xb = softmax(0.125 q @ kl^T) @ y2  (attn1)
    mflash_k<<<dim3(64, 1, NBH), 256, 0, stream>>>(
        qkvh, kl, y2, xb,
        1536, 64, 64, 512, NLAND, 0.125f,
        (ll)NTOK*1536, 64, 131072, 16384, 131072, 16384, (ll)NTOK*512, 64);

    // xb += depthwise_conv(v)
    dwconv_add_k<<<dim3(32, NBH), 256, 0, stream>>>(qkvh, cw, xb);

    // h = h + xb @ out_w + out_b
    mgemm<64,128,64,1,2,0,1><<<dim3(4, 256, 1), 256, 0, stream>>>(
        xb, owt, h, nullptr, ob, nullptr, nullptr,
        NBATCH*NTOK, DMODEL, DMODEL, DMODEL, DMODEL,
        0, 0, 0, 0.f, 0.f, 1|8);
  }

  head_k<<<4, 256, 0, stream>>>(h, fns, fnb, fcw, fcb, out);
}